// Round 1
// baseline (22100.194 us; speedup 1.0000x reference)
//
#include <hip/hip_runtime.h>
#include <hip/hip_bf16.h>
#include <math.h>

#define TS 256      // seq len
#define BS 32       // batch
#define NF 1024     // features
#define NH 16       // heads
#define HD 64       // head dim
#define PD 1024     // packed dim
#define FFD 4096    // feedforward
#define NLAYER 6
#define ROWS (TS*BS)   // 8192 tokens
#define LNEPS 1e-5f

// ---------------------------------------------------------------------------
// LayerNorm: one block (256 threads) per row of N=1024. float4 per thread.
// ---------------------------------------------------------------------------
__global__ __launch_bounds__(256)
void ln_kernel(const float* __restrict__ x, float* __restrict__ y,
               const float* __restrict__ g, const float* __restrict__ b) {
    int row = blockIdx.x;
    int tid = threadIdx.x;
    const float4* xr = (const float4*)(x + (size_t)row * NF);
    float4 v = xr[tid];
    float s  = v.x + v.y + v.z + v.w;
    float ss = v.x*v.x + v.y*v.y + v.z*v.z + v.w*v.w;
    #pragma unroll
    for (int off = 32; off > 0; off >>= 1) {
        s  += __shfl_down(s,  off);
        ss += __shfl_down(ss, off);
    }
    __shared__ float ws[4], wss[4];
    int wid = tid >> 6, lane = tid & 63;
    if (lane == 0) { ws[wid] = s; wss[wid] = ss; }
    __syncthreads();
    float sum  = ws[0] + ws[1] + ws[2] + ws[3];
    float sumsq = wss[0] + wss[1] + wss[2] + wss[3];
    float mean = sum * (1.0f / NF);
    float var  = sumsq * (1.0f / NF) - mean * mean;
    float rstd = rsqrtf(var + LNEPS);
    float4 gv = ((const float4*)g)[tid];
    float4 bv = ((const float4*)b)[tid];
    float4 o;
    o.x = (v.x - mean) * rstd * gv.x + bv.x;
    o.y = (v.y - mean) * rstd * gv.y + bv.y;
    o.z = (v.z - mean) * rstd * gv.z + bv.z;
    o.w = (v.w - mean) * rstd * gv.w + bv.w;
    ((float4*)(y + (size_t)row * NF))[tid] = o;
}

// ---------------------------------------------------------------------------
// GEMM (NT): C[M,N] = A[M,K] * B[N,K]^T + bias[N] (+resid) (+relu)
// 64x64 tile, BK=16, 256 threads, 4x4 acc per thread.
// ---------------------------------------------------------------------------
#define BM 64
#define BN 64
#define BK 16

__global__ __launch_bounds__(256)
void gemm_nt(const float* __restrict__ A, const float* __restrict__ Bm,
             const float* __restrict__ bias, const float* __restrict__ resid,
             float* __restrict__ C, int M, int N, int K, int relu) {
    __shared__ float As[BK][BM + 4];
    __shared__ float Bs[BK][BN + 4];
    int tid = threadIdx.x;
    int m0 = blockIdx.y * BM;
    int n0 = blockIdx.x * BN;
    int lr = tid >> 2;            // 0..63: row within tile
    int lk = (tid & 3) << 2;      // 0,4,8,12: k offset
    const float* Aptr = A + (size_t)(m0 + lr) * K + lk;
    const float* Bptr = Bm + (size_t)(n0 + lr) * K + lk;
    int tx = tid & 15, ty = tid >> 4;
    float acc[4][4] = {};
    for (int kt = 0; kt < K; kt += BK) {
        float4 av = *(const float4*)(Aptr + kt);
        float4 bv = *(const float4*)(Bptr + kt);
        __syncthreads();
        As[lk + 0][lr] = av.x; As[lk + 1][lr] = av.y;
        As[lk + 2][lr] = av.z; As[lk + 3][lr] = av.w;
        Bs[lk + 0][lr] = bv.x; Bs[lk + 1][lr] = bv.y;
        Bs[lk + 2][lr] = bv.z; Bs[lk + 3][lr] = bv.w;
        __syncthreads();
        #pragma unroll
        for (int kk = 0; kk < BK; kk++) {
            float4 a = *(const float4*)&As[kk][ty * 4];
            float4 b = *(const float4*)&Bs[kk][tx * 4];
            acc[0][0] += a.x * b.x; acc[0][1] += a.x * b.y;
            acc[0][2] += a.x * b.z; acc[0][3] += a.x * b.w;
            acc[1][0] += a.y * b.x; acc[1][1] += a.y * b.y;
            acc[1][2] += a.y * b.z; acc[1][3] += a.y * b.w;
            acc[2][0] += a.z * b.x; acc[2][1] += a.z * b.y;
            acc[2][2] += a.z * b.z; acc[2][3] += a.z * b.w;
            acc[3][0] += a.w * b.x; acc[3][1] += a.w * b.y;
            acc[3][2] += a.w * b.z; acc[3][3] += a.w * b.w;
        }
    }
    #pragma unroll
    for (int i = 0; i < 4; i++) {
        int row = m0 + ty * 4 + i;
        #pragma unroll
        for (int j = 0; j < 4; j++) {
            int col = n0 + tx * 4 + j;
            float val = acc[i][j] + bias[col];
            if (resid) val += resid[(size_t)row * N + col];
            if (relu) val = fmaxf(val, 0.0f);
            C[(size_t)row * N + col] = val;
        }
    }
}

// ---------------------------------------------------------------------------
// Attention: one block (256 threads) per (b,h). t tiled by 8.
// qkv layout: [T*B, 3*PD], row r = t*B+b; q at col h*64+d, k at PD+..., v 2PD+...
// ---------------------------------------------------------------------------
#define TT 8

__global__ __launch_bounds__(256)
void attn_kernel(const float* __restrict__ qkv, const float* __restrict__ mask,
                 float* __restrict__ o) {
    int bh = blockIdx.x;
    int b = bh >> 4;     // / NH
    int h = bh & 15;
    int tid = threadIdx.x;
    int lane = tid & 63, wid = tid >> 6;
    __shared__ float s_q[TT][HD];          // scaled q tile
    __shared__ float s_p[TT][TS];          // scores -> probs
    __shared__ float s_part[4][TT][HD];    // PV partials per wave
    const float inv = 0.125f;              // 1/sqrt(64)

    for (int t0 = 0; t0 < TS; t0 += TT) {
        __syncthreads();  // protect s_q / s_p reuse from previous tile readers
        // stage q tile (scaled)
        for (int i = tid; i < TT * HD; i += 256) {
            int tt = i >> 6, d = i & 63;
            s_q[tt][d] = qkv[(size_t)((t0 + tt) * BS + b) * (3 * PD) + h * HD + d] * inv;
        }
        __syncthreads();
        // phase 1: thread s computes scores for 8 t's
        {
            int s = tid;
            const float* krow = qkv + (size_t)(s * BS + b) * (3 * PD) + PD + h * HD;
            float sc[TT];
            #pragma unroll
            for (int tt = 0; tt < TT; tt++) sc[tt] = 0.0f;
            #pragma unroll
            for (int d4 = 0; d4 < HD; d4 += 4) {
                float4 kv = *(const float4*)(krow + d4);
                #pragma unroll
                for (int tt = 0; tt < TT; tt++) {
                    float4 qv = *(const float4*)&s_q[tt][d4];
                    sc[tt] += kv.x * qv.x + kv.y * qv.y + kv.z * qv.z + kv.w * qv.w;
                }
            }
            #pragma unroll
            for (int tt = 0; tt < TT; tt++)
                s_p[tt][s] = sc[tt] + mask[(size_t)(t0 + tt) * TS + s];
        }
        __syncthreads();
        // softmax: wave wid handles tt = wid and wid+4
        for (int tt = wid; tt < TT; tt += 4) {
            float v0 = s_p[tt][lane],       v1 = s_p[tt][lane + 64];
            float v2 = s_p[tt][lane + 128], v3 = s_p[tt][lane + 192];
            float m = fmaxf(fmaxf(v0, v1), fmaxf(v2, v3));
            #pragma unroll
            for (int off = 32; off > 0; off >>= 1) m = fmaxf(m, __shfl_down(m, off));
            m = __shfl(m, 0);
            v0 = __expf(v0 - m); v1 = __expf(v1 - m);
            v2 = __expf(v2 - m); v3 = __expf(v3 - m);
            float l = v0 + v1 + v2 + v3;
            #pragma unroll
            for (int off = 32; off > 0; off >>= 1) l += __shfl_down(l, off);
            l = __shfl(l, 0);
            float r = 1.0f / l;
            s_p[tt][lane]       = v0 * r; s_p[tt][lane + 64]  = v1 * r;
            s_p[tt][lane + 128] = v2 * r; s_p[tt][lane + 192] = v3 * r;
        }
        __syncthreads();
        // phase 2: wave wid covers s in [wid*64, wid*64+64); lane = d
        {
            int d = lane;
            float acc[TT];
            #pragma unroll
            for (int tt = 0; tt < TT; tt++) acc[tt] = 0.0f;
            const float* vbase = qkv + (size_t)b * (3 * PD) + 2 * PD + h * HD + d;
            #pragma unroll 4
            for (int j = 0; j < 64; j++) {
                int s = wid * 64 + j;
                float vv = vbase[(size_t)s * BS * (3 * PD)];
                #pragma unroll
                for (int tt = 0; tt < TT; tt++) acc[tt] += s_p[tt][s] * vv;
            }
            #pragma unroll
            for (int tt = 0; tt < TT; tt++) s_part[wid][tt][d] = acc[tt];
        }
        __syncthreads();
        // combine partials and write o
        {
            int tt = tid >> 6, d = tid & 63;
            #pragma unroll
            for (int k = 0; k < 2; k++, tt += 4) {
                float v = s_part[0][tt][d] + s_part[1][tt][d] +
                          s_part[2][tt][d] + s_part[3][tt][d];
                o[(size_t)((t0 + tt) * BS + b) * PD + h * HD + d] = v;
            }
        }
    }
}

// ---------------------------------------------------------------------------
extern "C" void kernel_launch(void* const* d_in, const int* in_sizes, int n_in,
                              void* d_out, int out_size, void* d_ws, size_t ws_size,
                              hipStream_t stream) {
    const float* src  = (const float*)d_in[0];
    const float* mask = (const float*)d_in[1];
    const float* Wqkv = (const float*)d_in[2];
    const float* bqkv = (const float*)d_in[3];
    const float* Wo   = (const float*)d_in[4];
    const float* bo   = (const float*)d_in[5];
    const float* ln1g = (const float*)d_in[6];
    const float* ln1b = (const float*)d_in[7];
    const float* ln2g = (const float*)d_in[8];
    const float* ln2b = (const float*)d_in[9];
    const float* W1   = (const float*)d_in[10];
    const float* b1   = (const float*)d_in[11];
    const float* W2   = (const float*)d_in[12];
    const float* b2   = (const float*)d_in[13];
    const float* lnfg = (const float*)d_in[14];
    const float* lnfb = (const float*)d_in[15];

    float* x = (float*)d_out;                              // activations [8192,1024]
    char* ws = (char*)d_ws;
    float* h   = (float*)ws;                               // 33.5 MB
    float* qkv = (float*)(ws + 33554432);                  // 100.7 MB
    float* o   = (float*)(ws + 33554432 + 100663296);      // 33.5 MB
    float* ff  = (float*)(ws + 33554432);                  // aliases qkv+o (134.2 MB)

    hipMemcpyAsync(x, src, (size_t)ROWS * NF * 4, hipMemcpyDeviceToDevice, stream);

    for (int l = 0; l < NLAYER; l++) {
        const float* wqkv_l = Wqkv + (size_t)l * 3 * PD * NF;
        const float* bqkv_l = bqkv + (size_t)l * 3 * PD;
        const float* wo_l   = Wo + (size_t)l * NF * PD;
        const float* bo_l   = bo + (size_t)l * NF;
        const float* w1_l   = W1 + (size_t)l * FFD * NF;
        const float* b1_l   = b1 + (size_t)l * FFD;
        const float* w2_l   = W2 + (size_t)l * NF * FFD;
        const float* b2_l   = b2 + (size_t)l * NF;

        // h = LN1(x)
        ln_kernel<<<ROWS, 256, 0, stream>>>(x, h, ln1g + (size_t)l * NF, ln1b + (size_t)l * NF);
        // qkv = h @ Wqkv^T + bqkv
        gemm_nt<<<dim3(3 * PD / BN, ROWS / BM), 256, 0, stream>>>(
            h, wqkv_l, bqkv_l, nullptr, qkv, ROWS, 3 * PD, NF, 0);
        // o = attention(qkv)
        attn_kernel<<<BS * NH, 256, 0, stream>>>(qkv, mask, o);
        // x = x + o @ Wo^T + bo
        gemm_nt<<<dim3(NF / BN, ROWS / BM), 256, 0, stream>>>(
            o, wo_l, bo_l, x, x, ROWS, NF, PD, 0);
        // h = LN2(x)
        ln_kernel<<<ROWS, 256, 0, stream>>>(x, h, ln2g + (size_t)l * NF, ln2b + (size_t)l * NF);
        // ff = relu(h @ W1^T + b1)
        gemm_nt<<<dim3(FFD / BN, ROWS / BM), 256, 0, stream>>>(
            h, w1_l, b1_l, nullptr, ff, ROWS, FFD, NF, 1);
        // x = x + ff @ W2^T + b2
        gemm_nt<<<dim3(NF / BN, ROWS / BM), 256, 0, stream>>>(
            ff, w2_l, b2_l, x, x, ROWS, NF, FFD, 0);
    }
    // final LN in place
    ln_kernel<<<ROWS, 256, 0, stream>>>(x, x, lnfg, lnfb);
}

// Round 2
// 6644.003 us; speedup vs baseline: 3.3263x; 3.3263x over previous
//
#include <hip/hip_runtime.h>
#include <math.h>

#define TS 256      // seq len
#define BS 32       // batch
#define NF 1024     // features
#define NH 16       // heads
#define HD 64       // head dim
#define PD 1024     // packed dim
#define FFD 4096    // feedforward
#define NLAYER 6
#define ROWS (TS*BS)   // 8192 tokens
#define LNEPS 1e-5f

typedef unsigned int u32;
typedef __attribute__((ext_vector_type(8))) short bf16x8;   // 8 bf16 = 4 VGPRs
typedef __attribute__((ext_vector_type(4))) float f32x4;

__device__ __forceinline__ unsigned short f2bf(float f) {
    u32 u = __builtin_bit_cast(u32, f);
    u32 r = (u + 0x7fffu + ((u >> 16) & 1u)) >> 16;   // RNE
    return (unsigned short)r;
}

// async global->LDS 16B copy (dest must be wave-uniform base + lane*16)
__device__ __forceinline__ void async16(const void* g, void* l) {
    __builtin_amdgcn_global_load_lds(
        (const __attribute__((address_space(1))) u32*)g,
        (__attribute__((address_space(3))) u32*)l, 16, 0, 0);
}

// ---------------------------------------------------------------------------
// LayerNorm: one block (256 threads) per row of N=1024. BF16OUT: emit bf16.
// ---------------------------------------------------------------------------
template <int BF16OUT>
__global__ __launch_bounds__(256)
void ln_kernel(const float* __restrict__ x, void* __restrict__ y,
               const float* __restrict__ g, const float* __restrict__ b) {
    int row = blockIdx.x;
    int tid = threadIdx.x;
    const float4* xr = (const float4*)(x + (size_t)row * NF);
    float4 v = xr[tid];
    float s  = v.x + v.y + v.z + v.w;
    float ss = v.x*v.x + v.y*v.y + v.z*v.z + v.w*v.w;
    #pragma unroll
    for (int off = 32; off > 0; off >>= 1) {
        s  += __shfl_down(s,  off);
        ss += __shfl_down(ss, off);
    }
    __shared__ float ws[4], wss[4];
    int wid = tid >> 6, lane = tid & 63;
    if (lane == 0) { ws[wid] = s; wss[wid] = ss; }
    __syncthreads();
    float sum   = ws[0] + ws[1] + ws[2] + ws[3];
    float sumsq = wss[0] + wss[1] + wss[2] + wss[3];
    float mean = sum * (1.0f / NF);
    float var  = sumsq * (1.0f / NF) - mean * mean;
    float rstd = rsqrtf(var + LNEPS);
    float4 gv = ((const float4*)g)[tid];
    float4 bv = ((const float4*)b)[tid];
    float4 o;
    o.x = (v.x - mean) * rstd * gv.x + bv.x;
    o.y = (v.y - mean) * rstd * gv.y + bv.y;
    o.z = (v.z - mean) * rstd * gv.z + bv.z;
    o.w = (v.w - mean) * rstd * gv.w + bv.w;
    if (BF16OUT) {
        ushort4 ov;
        ov.x = f2bf(o.x); ov.y = f2bf(o.y); ov.z = f2bf(o.z); ov.w = f2bf(o.w);
        ((ushort4*)((unsigned short*)y + (size_t)row * NF))[tid] = ov;
    } else {
        ((float4*)((float*)y + (size_t)row * NF))[tid] = o;
    }
}

// ---------------------------------------------------------------------------
// fp32 -> bf16 convert (n multiple of 4; grid = n/1024)
// ---------------------------------------------------------------------------
__global__ __launch_bounds__(256)
void f2bf_kernel(const float* __restrict__ in, unsigned short* __restrict__ out, int n) {
    int i = (blockIdx.x * 256 + threadIdx.x) * 4;
    if (i >= n) return;
    float4 v = *(const float4*)(in + i);
    ushort4 o;
    o.x = f2bf(v.x); o.y = f2bf(v.y); o.z = f2bf(v.z); o.w = f2bf(v.w);
    *(ushort4*)(out + i) = o;
}

// ---------------------------------------------------------------------------
// bf16 MFMA GEMM (NT): C[M,N] = A[M,K] * B[N,K]^T + bias[N]
// 128x128 tile, BK=32, 256 threads (4 waves, 2x2 quadrants of 64x64),
// 4x4 mfma_f32_16x16x32_bf16 per wave per K-step. global_load_lds width=16.
// XOR swizzle on k-chunks: LDS pos p holds global chunk p ^ ((row>>1)&3).
// MODE: 0 = fp32 row-major out (+optional resid), 1 = bf16 relu out,
//       2 = fp32 out in [3][B][H][T][HD] (QKV transpose for attention)
// ---------------------------------------------------------------------------
template <int MODE, int RESID>
__global__ __launch_bounds__(256)
void gemm_mfma(const unsigned short* __restrict__ A, const unsigned short* __restrict__ B,
               const float* __restrict__ bias, const float* __restrict__ resid,
               void* __restrict__ Cout, int M, int N, int K) {
    __shared__ __align__(16) unsigned short sA[128 * 32];
    __shared__ __align__(16) unsigned short sB[128 * 32];
    int tid = threadIdx.x;
    int m0 = blockIdx.y * 128, n0 = blockIdx.x * 128;

    // staging: load i = tid (+256); row = i>>2 (row+64 for second), chunk swizzled
    int row0 = tid >> 2;
    int c0 = (tid & 3) ^ ((row0 >> 1) & 3);      // same for row0+64
    const unsigned short* gA0 = A + (size_t)(m0 + row0) * K + c0 * 8;
    const unsigned short* gA1 = A + (size_t)(m0 + row0 + 64) * K + c0 * 8;
    const unsigned short* gB0 = B + (size_t)(n0 + row0) * K + c0 * 8;
    const unsigned short* gB1 = B + (size_t)(n0 + row0 + 64) * K + c0 * 8;
    unsigned short* lA0 = sA + tid * 8;
    unsigned short* lA1 = sA + (tid + 256) * 8;
    unsigned short* lB0 = sB + tid * 8;
    unsigned short* lB1 = sB + (tid + 256) * 8;

    int wid = tid >> 6, lane = tid & 63;
    int wm = wid >> 1, wn = wid & 1;
    int quad = lane >> 4, rl = lane & 15;

    int aoff[4], boff[4];
    #pragma unroll
    for (int t = 0; t < 4; t++) {
        int r = wm * 64 + t * 16 + rl;
        aoff[t] = r * 32 + (quad ^ ((r >> 1) & 3)) * 8;
        int rn = wn * 64 + t * 16 + rl;
        boff[t] = rn * 32 + (quad ^ ((rn >> 1) & 3)) * 8;
    }

    f32x4 acc[4][4] = {};

    for (int kt = 0; kt < K; kt += 32) {
        __syncthreads();                       // LDS free (prev compute done)
        async16(gA0 + kt, lA0);
        async16(gA1 + kt, lA1);
        async16(gB0 + kt, lB0);
        async16(gB1 + kt, lB1);
        __syncthreads();                       // staging drained (vmcnt(0))
        bf16x8 a[4], b[4];
        #pragma unroll
        for (int t = 0; t < 4; t++) {
            a[t] = *(const bf16x8*)(sA + aoff[t]);
            b[t] = *(const bf16x8*)(sB + boff[t]);
        }
        #pragma unroll
        for (int i = 0; i < 4; i++)
            #pragma unroll
            for (int j = 0; j < 4; j++)
                acc[i][j] = __builtin_amdgcn_mfma_f32_16x16x32_bf16(a[i], b[j], acc[i][j], 0, 0, 0);
    }

    // epilogue: C/D layout col=lane&15, row=quad*4+reg
    float bvv[4];
    #pragma unroll
    for (int nt = 0; nt < 4; nt++) bvv[nt] = bias[n0 + wn * 64 + nt * 16 + rl];
    #pragma unroll
    for (int mt = 0; mt < 4; mt++) {
        #pragma unroll
        for (int nt = 0; nt < 4; nt++) {
            #pragma unroll
            for (int r = 0; r < 4; r++) {
                int row = m0 + wm * 64 + mt * 16 + quad * 4 + r;
                int col = n0 + wn * 64 + nt * 16 + rl;
                float v = acc[mt][nt][r] + bvv[nt];
                if (MODE == 0) {
                    if (RESID) v += resid[(size_t)row * N + col];
                    ((float*)Cout)[(size_t)row * N + col] = v;
                } else if (MODE == 1) {
                    v = fmaxf(v, 0.0f);
                    ((unsigned short*)Cout)[(size_t)row * N + col] = f2bf(v);
                } else {
                    int t = row >> 5, bb = row & 31;          // row = t*BS+b
                    int s = col >> 10, h = (col >> 6) & 15, d = col & 63;
                    ((float*)Cout)[((((size_t)s * BS + bb) * NH + h) * TS + t) * HD + d] = v;
                }
            }
        }
    }
}

// ---------------------------------------------------------------------------
// Attention over qkvT [3][B][H][T][HD] fp32. One block (256 thr) per (b,h).
// Output o in [T,B,PD] bf16 (A-operand for the O-projection GEMM).
// ---------------------------------------------------------------------------
#define TT 8

__global__ __launch_bounds__(256)
void attn_kernel(const float* __restrict__ qkvT, const float* __restrict__ mask,
                 unsigned short* __restrict__ o) {
    int bh = blockIdx.x;           // b*NH + h
    int b = bh >> 4, h = bh & 15;
    const float* qB = qkvT + (size_t)bh * TS * HD;
    const float* kB = qB + (size_t)BS * NH * TS * HD;
    const float* vB = kB + (size_t)BS * NH * TS * HD;
    int tid = threadIdx.x;
    int lane = tid & 63, wid = tid >> 6;
    __shared__ float s_q[TT][HD];
    __shared__ float s_p[TT][TS];
    __shared__ float s_part[4][TT][HD];
    const float inv = 0.125f;      // 1/sqrt(64)

    for (int t0 = 0; t0 < TS; t0 += TT) {
        __syncthreads();
        for (int i = tid; i < TT * HD; i += 256) {
            int tt = i >> 6, d = i & 63;
            s_q[tt][d] = qB[(size_t)(t0 + tt) * HD + d] * inv;
        }
        __syncthreads();
        // scores: thread s over 8 t's, contiguous K rows
        {
            int s = tid;
            const float* krow = kB + (size_t)s * HD;
            float sc[TT];
            #pragma unroll
            for (int tt = 0; tt < TT; tt++) sc[tt] = 0.0f;
            #pragma unroll
            for (int d4 = 0; d4 < HD; d4 += 4) {
                float4 kv = *(const float4*)(krow + d4);
                #pragma unroll
                for (int tt = 0; tt < TT; tt++) {
                    float4 qv = *(const float4*)&s_q[tt][d4];
                    sc[tt] += kv.x * qv.x + kv.y * qv.y + kv.z * qv.z + kv.w * qv.w;
                }
            }
            #pragma unroll
            for (int tt = 0; tt < TT; tt++)
                s_p[tt][s] = sc[tt] + mask[(size_t)(t0 + tt) * TS + s];
        }
        __syncthreads();
        // softmax per t-row
        for (int tt = wid; tt < TT; tt += 4) {
            float v0 = s_p[tt][lane],       v1 = s_p[tt][lane + 64];
            float v2 = s_p[tt][lane + 128], v3 = s_p[tt][lane + 192];
            float m = fmaxf(fmaxf(v0, v1), fmaxf(v2, v3));
            #pragma unroll
            for (int off = 32; off > 0; off >>= 1) m = fmaxf(m, __shfl_down(m, off));
            m = __shfl(m, 0);
            v0 = __expf(v0 - m); v1 = __expf(v1 - m);
            v2 = __expf(v2 - m); v3 = __expf(v3 - m);
            float l = v0 + v1 + v2 + v3;
            #pragma unroll
            for (int off = 32; off > 0; off >>= 1) l += __shfl_down(l, off);
            l = __shfl(l, 0);
            float r = 1.0f / l;
            s_p[tt][lane]       = v0 * r; s_p[tt][lane + 64]  = v1 * r;
            s_p[tt][lane + 128] = v2 * r; s_p[tt][lane + 192] = v3 * r;
        }
        __syncthreads();
        // PV: wave wid covers s in [wid*64, wid*64+64); lane = d; V contiguous
        {
            int d = lane;
            float acc[TT];
            #pragma unroll
            for (int tt = 0; tt < TT; tt++) acc[tt] = 0.0f;
            #pragma unroll 4
            for (int j = 0; j < 64; j++) {
                int s = wid * 64 + j;
                float vv = vB[(size_t)s * HD + d];
                #pragma unroll
                for (int tt = 0; tt < TT; tt++) acc[tt] += s_p[tt][s] * vv;
            }
            #pragma unroll
            for (int tt = 0; tt < TT; tt++) s_part[wid][tt][d] = acc[tt];
        }
        __syncthreads();
        {
            int tt = tid >> 6, d = tid & 63;
            #pragma unroll
            for (int k = 0; k < 2; k++, tt += 4) {
                float v = s_part[0][tt][d] + s_part[1][tt][d] +
                          s_part[2][tt][d] + s_part[3][tt][d];
                o[(size_t)((t0 + tt) * BS + b) * PD + h * HD + d] = f2bf(v);
            }
        }
    }
}

// ---------------------------------------------------------------------------
extern "C" void kernel_launch(void* const* d_in, const int* in_sizes, int n_in,
                              void* d_out, int out_size, void* d_ws, size_t ws_size,
                              hipStream_t stream) {
    const float* src  = (const float*)d_in[0];
    const float* mask = (const float*)d_in[1];
    const float* Wqkv = (const float*)d_in[2];
    const float* bqkv = (const float*)d_in[3];
    const float* Wo   = (const float*)d_in[4];
    const float* bo   = (const float*)d_in[5];
    const float* ln1g = (const float*)d_in[6];
    const float* ln1b = (const float*)d_in[7];
    const float* ln2g = (const float*)d_in[8];
    const float* ln2b = (const float*)d_in[9];
    const float* W1   = (const float*)d_in[10];
    const float* b1   = (const float*)d_in[11];
    const float* W2   = (const float*)d_in[12];
    const float* b2   = (const float*)d_in[13];
    const float* lnfg = (const float*)d_in[14];
    const float* lnfb = (const float*)d_in[15];

    float* x = (float*)d_out;                                  // fp32 activations
    char* ws = (char*)d_ws;
    float*          qkvT = (float*)ws;                         // 100.66 MB [3][B][H][T][HD]
    unsigned short* ff   = (unsigned short*)ws;                // aliases qkvT (67.1 MB)
    unsigned short* h    = (unsigned short*)(ws + 100663296);  // 16.78 MB bf16
    unsigned short* o    = (unsigned short*)(ws + 117440512);  // 16.78 MB bf16
    unsigned short* wbuf = (unsigned short*)(ws + 134217728);  // 8.39 MB bf16 weights

    hipMemcpyAsync(x, src, (size_t)ROWS * NF * 4, hipMemcpyDeviceToDevice, stream);

    for (int l = 0; l < NLAYER; l++) {
        const float* wqkv_l = Wqkv + (size_t)l * 3 * PD * NF;
        const float* bqkv_l = bqkv + (size_t)l * 3 * PD;
        const float* wo_l   = Wo + (size_t)l * NF * PD;
        const float* bo_l   = bo + (size_t)l * NF;
        const float* w1_l   = W1 + (size_t)l * FFD * NF;
        const float* b1_l   = b1 + (size_t)l * FFD;
        const float* w2_l   = W2 + (size_t)l * NF * FFD;
        const float* b2_l   = b2 + (size_t)l * NF;

        // h = bf16(LN1(x))
        ln_kernel<1><<<ROWS, 256, 0, stream>>>(x, h, ln1g + (size_t)l * NF, ln1b + (size_t)l * NF);
        // qkvT = (h @ Wqkv^T + bqkv) in [3][B][H][T][HD]
        f2bf_kernel<<<3 * PD * NF / 1024, 256, 0, stream>>>(wqkv_l, wbuf, 3 * PD * NF);
        gemm_mfma<2, 0><<<dim3(3 * PD / 128, ROWS / 128), 256, 0, stream>>>(
            h, wbuf, bqkv_l, nullptr, qkvT, ROWS, 3 * PD, NF);
        // o = attention(qkvT)  (bf16, [T,B,PD])
        attn_kernel<<<BS * NH, 256, 0, stream>>>(qkvT, mask, o);
        // x = x + o @ Wo^T + bo
        f2bf_kernel<<<NF * PD / 1024, 256, 0, stream>>>(wo_l, wbuf, NF * PD);
        gemm_mfma<0, 1><<<dim3(NF / 128, ROWS / 128), 256, 0, stream>>>(
            o, wbuf, bo_l, x, x, ROWS, NF, PD);
        // h = bf16(LN2(x))
        ln_kernel<1><<<ROWS, 256, 0, stream>>>(x, h, ln2g + (size_t)l * NF, ln2b + (size_t)l * NF);
        // ff = bf16(relu(h @ W1^T + b1))
        f2bf_kernel<<<FFD * NF / 1024, 256, 0, stream>>>(w1_l, wbuf, FFD * NF);
        gemm_mfma<1, 0><<<dim3(FFD / 128, ROWS / 128), 256, 0, stream>>>(
            h, wbuf, b1_l, nullptr, ff, ROWS, FFD, NF);
        // x = x + ff @ W2^T + b2
        f2bf_kernel<<<NF * FFD / 1024, 256, 0, stream>>>(w2_l, wbuf, NF * FFD);
        gemm_mfma<0, 1><<<dim3(NF / 128, ROWS / 128), 256, 0, stream>>>(
            ff, wbuf, b2_l, x, x, ROWS, NF, FFD);
    }
    // final LN (fp32, in place on d_out)
    ln_kernel<0><<<ROWS, 256, 0, stream>>>(x, x, lnfg, lnfb);
}

// Round 3
// 2489.273 us; speedup vs baseline: 8.8782x; 2.6691x over previous
//
#include <hip/hip_runtime.h>
#include <math.h>

#define TS 256      // seq len
#define BS 32       // batch
#define NF 1024     // features
#define NH 16       // heads
#define HD 64       // head dim
#define PD 1024     // packed dim
#define FFD 4096    // feedforward
#define NLAYER 6
#define ROWS (TS*BS)   // 8192 tokens
#define LNEPS 1e-5f

typedef unsigned int u32;
typedef __attribute__((ext_vector_type(8))) short bf16x8;   // 8 bf16 = 4 VGPRs
typedef __attribute__((ext_vector_type(4))) float f32x4;

__device__ __forceinline__ unsigned short f2bf(float f) {
    u32 u = __builtin_bit_cast(u32, f);
    u32 r = (u + 0x7fffu + ((u >> 16) & 1u)) >> 16;   // RNE
    return (unsigned short)r;
}

// async global->LDS 16B copy (dest must be wave-uniform base + lane*16)
__device__ __forceinline__ void async16(const void* g, void* l) {
    __builtin_amdgcn_global_load_lds(
        (const __attribute__((address_space(1))) u32*)g,
        (__attribute__((address_space(3))) u32*)l, 16, 0, 0);
}

// ---------------------------------------------------------------------------
// LayerNorm: one block (256 threads) per row of N=1024. BF16OUT: emit bf16.
// ---------------------------------------------------------------------------
template <int BF16OUT>
__global__ __launch_bounds__(256)
void ln_kernel(const float* __restrict__ x, void* __restrict__ y,
               const float* __restrict__ g, const float* __restrict__ b) {
    int row = blockIdx.x;
    int tid = threadIdx.x;
    const float4* xr = (const float4*)(x + (size_t)row * NF);
    float4 v = xr[tid];
    float s  = v.x + v.y + v.z + v.w;
    float ss = v.x*v.x + v.y*v.y + v.z*v.z + v.w*v.w;
    #pragma unroll
    for (int off = 32; off > 0; off >>= 1) {
        s  += __shfl_down(s,  off);
        ss += __shfl_down(ss, off);
    }
    __shared__ float ws[4], wss[4];
    int wid = tid >> 6, lane = tid & 63;
    if (lane == 0) { ws[wid] = s; wss[wid] = ss; }
    __syncthreads();
    float sum   = ws[0] + ws[1] + ws[2] + ws[3];
    float sumsq = wss[0] + wss[1] + wss[2] + wss[3];
    float mean = sum * (1.0f / NF);
    float var  = sumsq * (1.0f / NF) - mean * mean;
    float rstd = rsqrtf(var + LNEPS);
    float4 gv = ((const float4*)g)[tid];
    float4 bv = ((const float4*)b)[tid];
    float4 o;
    o.x = (v.x - mean) * rstd * gv.x + bv.x;
    o.y = (v.y - mean) * rstd * gv.y + bv.y;
    o.z = (v.z - mean) * rstd * gv.z + bv.z;
    o.w = (v.w - mean) * rstd * gv.w + bv.w;
    if (BF16OUT) {
        ushort4 ov;
        ov.x = f2bf(o.x); ov.y = f2bf(o.y); ov.z = f2bf(o.z); ov.w = f2bf(o.w);
        ((ushort4*)((unsigned short*)y + (size_t)row * NF))[tid] = ov;
    } else {
        ((float4*)((float*)y + (size_t)row * NF))[tid] = o;
    }
}

// ---------------------------------------------------------------------------
// fp32 -> bf16 convert (n multiple of 4; grid = n/1024)
// ---------------------------------------------------------------------------
__global__ __launch_bounds__(256)
void f2bf_kernel(const float* __restrict__ in, unsigned short* __restrict__ out, int n) {
    int i = (blockIdx.x * 256 + threadIdx.x) * 4;
    if (i >= n) return;
    float4 v = *(const float4*)(in + i);
    ushort4 o;
    o.x = f2bf(v.x); o.y = f2bf(v.y); o.z = f2bf(v.z); o.w = f2bf(v.w);
    *(ushort4*)(out + i) = o;
}

// ---------------------------------------------------------------------------
// bf16 MFMA GEMM (NT): C[M,N] = A[M,K] * B[N,K]^T + bias[N]
// 128x128 tile, BK=32, 256 threads (4 waves, 2x2 quadrants of 64x64),
// 4x4 mfma_f32_16x16x32_bf16 per wave per K-step. global_load_lds width=16.
// XOR swizzle on k-chunks: LDS pos p holds global chunk p ^ ((row>>1)&3).
// MODE: 0 = fp32 row-major out (+optional resid), 1 = bf16 relu out,
//       2 = bf16 out in [3][B][H][T][HD] (QKV transpose for attention, q*0.125)
// ---------------------------------------------------------------------------
template <int MODE, int RESID>
__global__ __launch_bounds__(256)
void gemm_mfma(const unsigned short* __restrict__ A, const unsigned short* __restrict__ B,
               const float* __restrict__ bias, const float* __restrict__ resid,
               void* __restrict__ Cout, int M, int N, int K) {
    __shared__ __align__(16) unsigned short sA[128 * 32];
    __shared__ __align__(16) unsigned short sB[128 * 32];
    int tid = threadIdx.x;
    int m0 = blockIdx.y * 128, n0 = blockIdx.x * 128;

    int row0 = tid >> 2;
    int c0 = (tid & 3) ^ ((row0 >> 1) & 3);      // same for row0+64
    const unsigned short* gA0 = A + (size_t)(m0 + row0) * K + c0 * 8;
    const unsigned short* gA1 = A + (size_t)(m0 + row0 + 64) * K + c0 * 8;
    const unsigned short* gB0 = B + (size_t)(n0 + row0) * K + c0 * 8;
    const unsigned short* gB1 = B + (size_t)(n0 + row0 + 64) * K + c0 * 8;
    unsigned short* lA0 = sA + tid * 8;
    unsigned short* lA1 = sA + (tid + 256) * 8;
    unsigned short* lB0 = sB + tid * 8;
    unsigned short* lB1 = sB + (tid + 256) * 8;

    int wid = tid >> 6, lane = tid & 63;
    int wm = wid >> 1, wn = wid & 1;
    int quad = lane >> 4, rl = lane & 15;

    int aoff[4], boff[4];
    #pragma unroll
    for (int t = 0; t < 4; t++) {
        int r = wm * 64 + t * 16 + rl;
        aoff[t] = r * 32 + (quad ^ ((r >> 1) & 3)) * 8;
        int rn = wn * 64 + t * 16 + rl;
        boff[t] = rn * 32 + (quad ^ ((rn >> 1) & 3)) * 8;
    }

    f32x4 acc[4][4] = {};

    for (int kt = 0; kt < K; kt += 32) {
        __syncthreads();
        async16(gA0 + kt, lA0);
        async16(gA1 + kt, lA1);
        async16(gB0 + kt, lB0);
        async16(gB1 + kt, lB1);
        __syncthreads();
        bf16x8 a[4], b[4];
        #pragma unroll
        for (int t = 0; t < 4; t++) {
            a[t] = *(const bf16x8*)(sA + aoff[t]);
            b[t] = *(const bf16x8*)(sB + boff[t]);
        }
        #pragma unroll
        for (int i = 0; i < 4; i++)
            #pragma unroll
            for (int j = 0; j < 4; j++)
                acc[i][j] = __builtin_amdgcn_mfma_f32_16x16x32_bf16(a[i], b[j], acc[i][j], 0, 0, 0);
    }

    float bvv[4];
    #pragma unroll
    for (int nt = 0; nt < 4; nt++) bvv[nt] = bias[n0 + wn * 64 + nt * 16 + rl];
    #pragma unroll
    for (int mt = 0; mt < 4; mt++) {
        #pragma unroll
        for (int nt = 0; nt < 4; nt++) {
            #pragma unroll
            for (int r = 0; r < 4; r++) {
                int row = m0 + wm * 64 + mt * 16 + quad * 4 + r;
                int col = n0 + wn * 64 + nt * 16 + rl;
                float v = acc[mt][nt][r] + bvv[nt];
                if (MODE == 0) {
                    if (RESID) v += resid[(size_t)row * N + col];
                    ((float*)Cout)[(size_t)row * N + col] = v;
                } else if (MODE == 1) {
                    v = fmaxf(v, 0.0f);
                    ((unsigned short*)Cout)[(size_t)row * N + col] = f2bf(v);
                } else {
                    int t = row >> 5, bb = row & 31;          // row = t*BS+b
                    int s = col >> 10, hh = (col >> 6) & 15, d = col & 63;
                    if (s == 0) v *= 0.125f;                  // q pre-scale (exact)
                    ((unsigned short*)Cout)[((((size_t)s * BS + bb) * NH + hh) * TS + t) * HD + d] = f2bf(v);
                }
            }
        }
    }
}

// ---------------------------------------------------------------------------
// MFMA attention. qkvT: bf16 [3][B][H][T][HD] (q pre-scaled by 1/8).
// Grid = B*NH*2; block bx: bh = bx>>1, half = bx&1 -> 128 Q-rows.
// 4 waves x 32 rows. K in LDS [256][72]; V^T in LDS [64][264]; per-wave
// P-transpose scratch [32][40]. Output o bf16 [T,B,PD].
// ---------------------------------------------------------------------------
__global__ __launch_bounds__(256, 2)
void attn_mfma(const unsigned short* __restrict__ qkvT, const float* __restrict__ mask,
               unsigned short* __restrict__ o) {
    int bx = blockIdx.x;
    int bh = bx >> 1, half = bx & 1;
    int b = bh >> 4, h = bh & 15;
    const unsigned short* qB = qkvT + (size_t)bh * TS * HD;
    const unsigned short* kB = qB + (size_t)BS * NH * TS * HD;
    const unsigned short* vB = kB + (size_t)BS * NH * TS * HD;
    int tid = threadIdx.x, lane = tid & 63, wid = tid >> 6;
    int quad = lane >> 4, rl = lane & 15;
    int tbase = half * 128 + wid * 32;            // this wave's 32 Q-rows

    __shared__ __align__(16) unsigned short sKV[18432];   // K [256][72] then Vt [64][264]
    __shared__ __align__(16) unsigned short sP[4][1280];  // per-wave P scratch [32][40]

    // stage K [256 s][72] (rows 16B-aligned, stride 144 B -> conflict-free b128)
    #pragma unroll
    for (int it = 0; it < 8; it++) {
        int idx = it * 256 + tid, rrow = idx >> 3, ch = idx & 7;
        *(uint4*)(sKV + rrow * 72 + ch * 8) = *(const uint4*)(kB + (size_t)rrow * 64 + ch * 8);
    }

    // Q fragments (global, already scaled)
    bf16x8 qf[2][2];
    #pragma unroll
    for (int mt = 0; mt < 2; mt++)
        #pragma unroll
        for (int ks = 0; ks < 2; ks++)
            qf[mt][ks] = *(const bf16x8*)(qB + (size_t)(tbase + mt * 16 + rl) * 64 + ks * 32 + quad * 8);

    __syncthreads();

    // scores S[t][s]: A = Q rows, B = K rows
    f32x4 S[2][16] = {};
    #pragma unroll
    for (int nt = 0; nt < 16; nt++) {
        bf16x8 k0 = *(const bf16x8*)(sKV + (nt * 16 + rl) * 72 + quad * 8);
        bf16x8 k1 = *(const bf16x8*)(sKV + (nt * 16 + rl) * 72 + 32 + quad * 8);
        #pragma unroll
        for (int mt = 0; mt < 2; mt++) {
            S[mt][nt] = __builtin_amdgcn_mfma_f32_16x16x32_bf16(qf[mt][0], k0, S[mt][nt], 0, 0, 0);
            S[mt][nt] = __builtin_amdgcn_mfma_f32_16x16x32_bf16(qf[mt][1], k1, S[mt][nt], 0, 0, 0);
        }
    }

    // mask + softmax, rows t = tbase + mt*16 + quad*4 + r, cols s = nt*16 + rl
    float linv[2][4];
    #pragma unroll
    for (int mt = 0; mt < 2; mt++) {
        #pragma unroll
        for (int r = 0; r < 4; r++) {
            int tg = tbase + mt * 16 + quad * 4 + r;
            const float* mrow = mask + (size_t)tg * TS + rl;
            float mx = -3.0e38f;
            #pragma unroll
            for (int nt = 0; nt < 16; nt++) {
                S[mt][nt][r] += mrow[nt * 16];
                mx = fmaxf(mx, S[mt][nt][r]);
            }
            mx = fmaxf(mx, __shfl_xor(mx, 1));
            mx = fmaxf(mx, __shfl_xor(mx, 2));
            mx = fmaxf(mx, __shfl_xor(mx, 4));
            mx = fmaxf(mx, __shfl_xor(mx, 8));
            float sum = 0.0f;
            #pragma unroll
            for (int nt = 0; nt < 16; nt++) {
                float p = __expf(S[mt][nt][r] - mx);
                S[mt][nt][r] = p;
                sum += p;
            }
            sum += __shfl_xor(sum, 1);
            sum += __shfl_xor(sum, 2);
            sum += __shfl_xor(sum, 4);
            sum += __shfl_xor(sum, 8);
            linv[mt][r] = 1.0f / sum;
        }
    }

    __syncthreads();   // all waves done reading K
    // stage V transposed: Vt [64 d][264 s]
    #pragma unroll
    for (int it = 0; it < 8; it++) {
        int idx = it * 256 + tid, srow = idx >> 3, dc = idx & 7;
        bf16x8 vv = *(const bf16x8*)(vB + (size_t)srow * 64 + dc * 8);
        #pragma unroll
        for (int j = 0; j < 8; j++)
            sKV[(dc * 8 + j) * 264 + srow] = (unsigned short)vv[j];
    }
    __syncthreads();

    // PV: O[t][d] = sum_s P[t][s] Vt[d][s]; per-wave P transpose via scratch
    f32x4 O[2][4] = {};
    unsigned short* myP = sP[wid];
    #pragma unroll
    for (int sc = 0; sc < 8; sc++) {
        #pragma unroll
        for (int mt = 0; mt < 2; mt++)
            #pragma unroll
            for (int hi = 0; hi < 2; hi++)
                #pragma unroll
                for (int r = 0; r < 4; r++)
                    myP[(mt * 16 + quad * 4 + r) * 40 + hi * 16 + rl] = f2bf(S[mt][2 * sc + hi][r]);
        bf16x8 pa[2], vf[4];
        #pragma unroll
        for (int mt = 0; mt < 2; mt++)
            pa[mt] = *(const bf16x8*)(myP + (mt * 16 + rl) * 40 + quad * 8);
        #pragma unroll
        for (int nd = 0; nd < 4; nd++)
            vf[nd] = *(const bf16x8*)(sKV + (nd * 16 + rl) * 264 + sc * 32 + quad * 8);
        #pragma unroll
        for (int mt = 0; mt < 2; mt++)
            #pragma unroll
            for (int nd = 0; nd < 4; nd++)
                O[mt][nd] = __builtin_amdgcn_mfma_f32_16x16x32_bf16(pa[mt], vf[nd], O[mt][nd], 0, 0, 0);
    }

    // epilogue: normalize by 1/l, write o [T,B,PD] bf16
    #pragma unroll
    for (int mt = 0; mt < 2; mt++)
        #pragma unroll
        for (int nd = 0; nd < 4; nd++)
            #pragma unroll
            for (int r = 0; r < 4; r++) {
                int tg = tbase + mt * 16 + quad * 4 + r;
                int d = nd * 16 + rl;
                o[(size_t)(tg * BS + b) * PD + h * HD + d] = f2bf(O[mt][nd][r] * linv[mt][r]);
            }
}

// ---------------------------------------------------------------------------
extern "C" void kernel_launch(void* const* d_in, const int* in_sizes, int n_in,
                              void* d_out, int out_size, void* d_ws, size_t ws_size,
                              hipStream_t stream) {
    const float* src  = (const float*)d_in[0];
    const float* mask = (const float*)d_in[1];
    const float* Wqkv = (const float*)d_in[2];
    const float* bqkv = (const float*)d_in[3];
    const float* Wo   = (const float*)d_in[4];
    const float* bo   = (const float*)d_in[5];
    const float* ln1g = (const float*)d_in[6];
    const float* ln1b = (const float*)d_in[7];
    const float* ln2g = (const float*)d_in[8];
    const float* ln2b = (const float*)d_in[9];
    const float* W1   = (const float*)d_in[10];
    const float* b1   = (const float*)d_in[11];
    const float* W2   = (const float*)d_in[12];
    const float* b2   = (const float*)d_in[13];
    const float* lnfg = (const float*)d_in[14];
    const float* lnfb = (const float*)d_in[15];

    float* x = (float*)d_out;                                  // fp32 activations
    char* ws = (char*)d_ws;
    unsigned short* qkvT = (unsigned short*)ws;                // 50.3 MB bf16 [3][B][H][T][HD]
    unsigned short* ff   = (unsigned short*)ws;                // aliases qkvT (67.1 MB bf16)
    unsigned short* h    = (unsigned short*)(ws + 100663296);  // 16.78 MB bf16
    unsigned short* o    = (unsigned short*)(ws + 117440512);  // 16.78 MB bf16
    unsigned short* wbuf = (unsigned short*)(ws + 134217728);  // 8.39 MB bf16 weights

    hipMemcpyAsync(x, src, (size_t)ROWS * NF * 4, hipMemcpyDeviceToDevice, stream);

    for (int l = 0; l < NLAYER; l++) {
        const float* wqkv_l = Wqkv + (size_t)l * 3 * PD * NF;
        const float* bqkv_l = bqkv + (size_t)l * 3 * PD;
        const float* wo_l   = Wo + (size_t)l * NF * PD;
        const float* bo_l   = bo + (size_t)l * NF;
        const float* w1_l   = W1 + (size_t)l * FFD * NF;
        const float* b1_l   = b1 + (size_t)l * FFD;
        const float* w2_l   = W2 + (size_t)l * NF * FFD;
        const float* b2_l   = b2 + (size_t)l * NF;

        // h = bf16(LN1(x))
        ln_kernel<1><<<ROWS, 256, 0, stream>>>(x, h, ln1g + (size_t)l * NF, ln1b + (size_t)l * NF);
        // qkvT = (h @ Wqkv^T + bqkv) -> bf16 [3][B][H][T][HD], q scaled
        f2bf_kernel<<<3 * PD * NF / 1024, 256, 0, stream>>>(wqkv_l, wbuf, 3 * PD * NF);
        gemm_mfma<2, 0><<<dim3(3 * PD / 128, ROWS / 128), 256, 0, stream>>>(
            h, wbuf, bqkv_l, nullptr, qkvT, ROWS, 3 * PD, NF);
        // o = attention(qkvT)  (bf16, [T,B,PD])
        attn_mfma<<<BS * NH * 2, 256, 0, stream>>>(qkvT, mask, o);
        // x = x + o @ Wo^T + bo
        f2bf_kernel<<<NF * PD / 1024, 256, 0, stream>>>(wo_l, wbuf, NF * PD);
        gemm_mfma<0, 1><<<dim3(NF / 128, ROWS / 128), 256, 0, stream>>>(
            o, wbuf, bo_l, x, x, ROWS, NF, PD);
        // h = bf16(LN2(x))
        ln_kernel<1><<<ROWS, 256, 0, stream>>>(x, h, ln2g + (size_t)l * NF, ln2b + (size_t)l * NF);
        // ff = bf16(relu(h @ W1^T + b1))
        f2bf_kernel<<<FFD * NF / 1024, 256, 0, stream>>>(w1_l, wbuf, FFD * NF);
        gemm_mfma<1, 0><<<dim3(FFD / 128, ROWS / 128), 256, 0, stream>>>(
            h, wbuf, b1_l, nullptr, ff, ROWS, FFD, NF);
        // x = x + ff @ W2^T + b2
        f2bf_kernel<<<NF * FFD / 1024, 256, 0, stream>>>(w2_l, wbuf, NF * FFD);
        gemm_mfma<0, 1><<<dim3(NF / 128, ROWS / 128), 256, 0, stream>>>(
            ff, wbuf, b2_l, x, x, ROWS, NF, FFD);
    }
    // final LN (fp32, in place on d_out)
    ln_kernel<0><<<ROWS, 256, 0, stream>>>(x, x, lnfg, lnfb);
}

// Round 4
// 2208.750 us; speedup vs baseline: 10.0057x; 1.1270x over previous
//
#include <hip/hip_runtime.h>
#include <math.h>

#define TS 256      // seq len
#define BS 32       // batch
#define NF 1024     // features
#define NH 16       // heads
#define HD 64       // head dim
#define PD 1024     // packed dim
#define FFD 4096    // feedforward
#define NLAYER 6
#define ROWS (TS*BS)   // 8192 tokens
#define LNEPS 1e-5f

typedef unsigned int u32;
typedef __attribute__((ext_vector_type(8))) short bf16x8;   // 8 bf16 = 4 VGPRs
typedef __attribute__((ext_vector_type(4))) float f32x4;

__device__ __forceinline__ unsigned short f2bf(float f) {
    u32 u = __builtin_bit_cast(u32, f);
    u32 r = (u + 0x7fffu + ((u >> 16) & 1u)) >> 16;   // RNE
    return (unsigned short)r;
}

// async global->LDS 16B copy (dest must be wave-uniform base + lane*16)
__device__ __forceinline__ void async16(const void* g, void* l) {
    __builtin_amdgcn_global_load_lds(
        (const __attribute__((address_space(1))) u32*)g,
        (__attribute__((address_space(3))) u32*)l, 16, 0, 0);
}

// ---------------------------------------------------------------------------
// LayerNorm: one block (256 threads) per row of N=1024. BF16OUT: emit bf16.
// ---------------------------------------------------------------------------
template <int BF16OUT>
__global__ __launch_bounds__(256)
void ln_kernel(const float* __restrict__ x, void* __restrict__ y,
               const float* __restrict__ g, const float* __restrict__ b) {
    int row = blockIdx.x;
    int tid = threadIdx.x;
    const float4* xr = (const float4*)(x + (size_t)row * NF);
    float4 v = xr[tid];
    float s  = v.x + v.y + v.z + v.w;
    float ss = v.x*v.x + v.y*v.y + v.z*v.z + v.w*v.w;
    #pragma unroll
    for (int off = 32; off > 0; off >>= 1) {
        s  += __shfl_down(s,  off);
        ss += __shfl_down(ss, off);
    }
    __shared__ float ws[4], wss[4];
    int wid = tid >> 6, lane = tid & 63;
    if (lane == 0) { ws[wid] = s; wss[wid] = ss; }
    __syncthreads();
    float sum   = ws[0] + ws[1] + ws[2] + ws[3];
    float sumsq = wss[0] + wss[1] + wss[2] + wss[3];
    float mean = sum * (1.0f / NF);
    float var  = sumsq * (1.0f / NF) - mean * mean;
    float rstd = rsqrtf(var + LNEPS);
    float4 gv = ((const float4*)g)[tid];
    float4 bv = ((const float4*)b)[tid];
    float4 o;
    o.x = (v.x - mean) * rstd * gv.x + bv.x;
    o.y = (v.y - mean) * rstd * gv.y + bv.y;
    o.z = (v.z - mean) * rstd * gv.z + bv.z;
    o.w = (v.w - mean) * rstd * gv.w + bv.w;
    if (BF16OUT) {
        ushort4 ov;
        ov.x = f2bf(o.x); ov.y = f2bf(o.y); ov.z = f2bf(o.z); ov.w = f2bf(o.w);
        ((ushort4*)((unsigned short*)y + (size_t)row * NF))[tid] = ov;
    } else {
        ((float4*)((float*)y + (size_t)row * NF))[tid] = o;
    }
}

// ---------------------------------------------------------------------------
// fp32 -> bf16 convert, 4 arrays in one launch (blockIdx.y selects array)
// ---------------------------------------------------------------------------
__global__ __launch_bounds__(256)
void f2bf4_kernel(const float* __restrict__ s0, const float* __restrict__ s1,
                  const float* __restrict__ s2, const float* __restrict__ s3,
                  unsigned short* __restrict__ d0, unsigned short* __restrict__ d1,
                  unsigned short* __restrict__ d2, unsigned short* __restrict__ d3,
                  int n0, int n1, int n2, int n3) {
    const float* s; unsigned short* d; int n;
    switch (blockIdx.y) {
        case 0: s = s0; d = d0; n = n0; break;
        case 1: s = s1; d = d1; n = n1; break;
        case 2: s = s2; d = d2; n = n2; break;
        default: s = s3; d = d3; n = n3; break;
    }
    int i = (blockIdx.x * 256 + threadIdx.x) * 4;
    if (i >= n) return;
    float4 v = *(const float4*)(s + i);
    ushort4 o;
    o.x = f2bf(v.x); o.y = f2bf(v.y); o.z = f2bf(v.z); o.w = f2bf(v.w);
    *(ushort4*)(d + i) = o;
}

// ---------------------------------------------------------------------------
// bf16 MFMA GEMM (NT): C[M,N] = A[M,K] * B[N,K]^T + bias[N]
// 128x128 tile, BK=64, 256 threads (4 waves, 2x2 quadrants of 64x64),
// 2 k-steps x 16 mfma_f32_16x16x32_bf16 per wave per iter. GLD width=16.
// LDS rows 64 elems; chunk swizzle: position p holds chunk p ^ (row&7).
// 1D grid, grouped ordering (8 m-blocks per group, n fast).
// MODE: 0 = fp32 row-major out (+optional resid), 1 = bf16 relu out,
//       2 = bf16 out in [3][B][H][T][HD] (QKV transpose, q*0.125)
// ---------------------------------------------------------------------------
template <int MODE, int RESID>
__global__ __launch_bounds__(256)
void gemm_mfma(const unsigned short* __restrict__ A, const unsigned short* __restrict__ B,
               const float* __restrict__ bias, const float* __restrict__ resid,
               void* __restrict__ Cout, int M, int N, int K) {
    __shared__ __align__(16) unsigned short sA[128 * 64];
    __shared__ __align__(16) unsigned short sB[128 * 64];
    int tid = threadIdx.x;

    // grouped block swizzle: groups of 8 m-blocks x all n-blocks, n fast
    int Nb = N >> 7;
    int bid = blockIdx.x;
    int group = bid / (8 * Nb);
    int rem = bid - group * (8 * Nb);
    int m0 = (group * 8 + rem / Nb) * 128;
    int n0 = (rem % Nb) * 128;

    // staging: 1024 chunks of 8 elems per tile; thread covers idx = tid + 256*it
    int rB = tid >> 3;                       // base row (it=0); row_it = rB + 32*it
    int c0 = (tid & 7) ^ (rB & 7);           // global chunk (same for all it)
    const unsigned short* gA[4];
    const unsigned short* gB[4];
    #pragma unroll
    for (int it = 0; it < 4; it++) {
        gA[it] = A + (size_t)(m0 + rB + 32 * it) * K + c0 * 8;
        gB[it] = B + (size_t)(n0 + rB + 32 * it) * K + c0 * 8;
    }

    int wid = tid >> 6, lane = tid & 63;
    int wm = wid >> 1, wn = wid & 1;
    int quad = lane >> 4, rl = lane & 15;

    int aoff[2][4], boff[2][4];
    #pragma unroll
    for (int ks = 0; ks < 2; ks++)
        #pragma unroll
        for (int t = 0; t < 4; t++) {
            int r = wm * 64 + t * 16 + rl;
            aoff[ks][t] = r * 64 + ((ks * 4 + quad) ^ (r & 7)) * 8;
            int rn = wn * 64 + t * 16 + rl;
            boff[ks][t] = rn * 64 + ((ks * 4 + quad) ^ (rn & 7)) * 8;
        }

    f32x4 acc[4][4] = {};

    for (int kt = 0; kt < K; kt += 64) {
        __syncthreads();
        #pragma unroll
        for (int it = 0; it < 4; it++) {
            async16(gA[it] + kt, sA + (tid + 256 * it) * 8);
            async16(gB[it] + kt, sB + (tid + 256 * it) * 8);
        }
        __syncthreads();
        #pragma unroll
        for (int ks = 0; ks < 2; ks++) {
            bf16x8 a[4], b[4];
            #pragma unroll
            for (int t = 0; t < 4; t++) {
                a[t] = *(const bf16x8*)(sA + aoff[ks][t]);
                b[t] = *(const bf16x8*)(sB + boff[ks][t]);
            }
            #pragma unroll
            for (int i = 0; i < 4; i++)
                #pragma unroll
                for (int j = 0; j < 4; j++)
                    acc[i][j] = __builtin_amdgcn_mfma_f32_16x16x32_bf16(a[i], b[j], acc[i][j], 0, 0, 0);
        }
    }

    // epilogue: C/D layout col=lane&15, row=quad*4+reg
    float bvv[4];
    #pragma unroll
    for (int nt = 0; nt < 4; nt++) bvv[nt] = bias[n0 + wn * 64 + nt * 16 + rl];
    #pragma unroll
    for (int mt = 0; mt < 4; mt++) {
        #pragma unroll
        for (int nt = 0; nt < 4; nt++) {
            #pragma unroll
            for (int r = 0; r < 4; r++) {
                int row = m0 + wm * 64 + mt * 16 + quad * 4 + r;
                int col = n0 + wn * 64 + nt * 16 + rl;
                float v = acc[mt][nt][r] + bvv[nt];
                if (MODE == 0) {
                    if (RESID) v += resid[(size_t)row * N + col];
                    ((float*)Cout)[(size_t)row * N + col] = v;
                } else if (MODE == 1) {
                    v = fmaxf(v, 0.0f);
                    ((unsigned short*)Cout)[(size_t)row * N + col] = f2bf(v);
                } else {
                    int t = row >> 5, bb = row & 31;          // row = t*BS+b
                    int s = col >> 10, hh = (col >> 6) & 15, d = col & 63;
                    if (s == 0) v *= 0.125f;                  // q pre-scale (exact)
                    ((unsigned short*)Cout)[((((size_t)s * BS + bb) * NH + hh) * TS + t) * HD + d] = f2bf(v);
                }
            }
        }
    }
}

// ---------------------------------------------------------------------------
// MFMA attention. qkvT: bf16 [3][B][H][T][HD] (q pre-scaled by 1/8).
// Grid = B*NH*2; block bx: bh = bx>>1, half = bx&1 -> 128 Q-rows.
// 4 waves x 32 rows. K in LDS [256][72]; V^T in LDS [64][264]; per-wave
// P-transpose scratch [32][40]. Output o bf16 [T,B,PD].
// ---------------------------------------------------------------------------
__global__ __launch_bounds__(256, 2)
void attn_mfma(const unsigned short* __restrict__ qkvT, const float* __restrict__ mask,
               unsigned short* __restrict__ o) {
    int bx = blockIdx.x;
    int bh = bx >> 1, half = bx & 1;
    int b = bh >> 4, h = bh & 15;
    const unsigned short* qB = qkvT + (size_t)bh * TS * HD;
    const unsigned short* kB = qB + (size_t)BS * NH * TS * HD;
    const unsigned short* vB = kB + (size_t)BS * NH * TS * HD;
    int tid = threadIdx.x, lane = tid & 63, wid = tid >> 6;
    int quad = lane >> 4, rl = lane & 15;
    int tbase = half * 128 + wid * 32;            // this wave's 32 Q-rows

    __shared__ __align__(16) unsigned short sKV[18432];   // K [256][72] then Vt [64][264]
    __shared__ __align__(16) unsigned short sP[4][1280];  // per-wave P scratch [32][40]

    // stage K [256 s][72]
    #pragma unroll
    for (int it = 0; it < 8; it++) {
        int idx = it * 256 + tid, rrow = idx >> 3, ch = idx & 7;
        *(uint4*)(sKV + rrow * 72 + ch * 8) = *(const uint4*)(kB + (size_t)rrow * 64 + ch * 8);
    }

    // Q fragments (global, already scaled)
    bf16x8 qf[2][2];
    #pragma unroll
    for (int mt = 0; mt < 2; mt++)
        #pragma unroll
        for (int ks = 0; ks < 2; ks++)
            qf[mt][ks] = *(const bf16x8*)(qB + (size_t)(tbase + mt * 16 + rl) * 64 + ks * 32 + quad * 8);

    __syncthreads();

    // scores S[t][s]: A = Q rows, B = K rows
    f32x4 S[2][16] = {};
    #pragma unroll
    for (int nt = 0; nt < 16; nt++) {
        bf16x8 k0 = *(const bf16x8*)(sKV + (nt * 16 + rl) * 72 + quad * 8);
        bf16x8 k1 = *(const bf16x8*)(sKV + (nt * 16 + rl) * 72 + 32 + quad * 8);
        #pragma unroll
        for (int mt = 0; mt < 2; mt++) {
            S[mt][nt] = __builtin_amdgcn_mfma_f32_16x16x32_bf16(qf[mt][0], k0, S[mt][nt], 0, 0, 0);
            S[mt][nt] = __builtin_amdgcn_mfma_f32_16x16x32_bf16(qf[mt][1], k1, S[mt][nt], 0, 0, 0);
        }
    }

    // mask + softmax, rows t = tbase + mt*16 + quad*4 + r, cols s = nt*16 + rl
    float linv[2][4];
    #pragma unroll
    for (int mt = 0; mt < 2; mt++) {
        #pragma unroll
        for (int r = 0; r < 4; r++) {
            int tg = tbase + mt * 16 + quad * 4 + r;
            const float* mrow = mask + (size_t)tg * TS + rl;
            float mx = -3.0e38f;
            #pragma unroll
            for (int nt = 0; nt < 16; nt++) {
                S[mt][nt][r] += mrow[nt * 16];
                mx = fmaxf(mx, S[mt][nt][r]);
            }
            mx = fmaxf(mx, __shfl_xor(mx, 1));
            mx = fmaxf(mx, __shfl_xor(mx, 2));
            mx = fmaxf(mx, __shfl_xor(mx, 4));
            mx = fmaxf(mx, __shfl_xor(mx, 8));
            float sum = 0.0f;
            #pragma unroll
            for (int nt = 0; nt < 16; nt++) {
                float p = __expf(S[mt][nt][r] - mx);
                S[mt][nt][r] = p;
                sum += p;
            }
            sum += __shfl_xor(sum, 1);
            sum += __shfl_xor(sum, 2);
            sum += __shfl_xor(sum, 4);
            sum += __shfl_xor(sum, 8);
            linv[mt][r] = 1.0f / sum;
        }
    }

    __syncthreads();   // all waves done reading K
    // stage V transposed: Vt [64 d][264 s]
    #pragma unroll
    for (int it = 0; it < 8; it++) {
        int idx = it * 256 + tid, srow = idx >> 3, dc = idx & 7;
        bf16x8 vv = *(const bf16x8*)(vB + (size_t)srow * 64 + dc * 8);
        #pragma unroll
        for (int j = 0; j < 8; j++)
            sKV[(dc * 8 + j) * 264 + srow] = (unsigned short)vv[j];
    }
    __syncthreads();

    // PV: O[t][d] = sum_s P[t][s] Vt[d][s]; per-wave P transpose via scratch
    f32x4 O[2][4] = {};
    unsigned short* myP = sP[wid];
    #pragma unroll
    for (int sc = 0; sc < 8; sc++) {
        #pragma unroll
        for (int mt = 0; mt < 2; mt++)
            #pragma unroll
            for (int hi = 0; hi < 2; hi++)
                #pragma unroll
                for (int r = 0; r < 4; r++)
                    myP[(mt * 16 + quad * 4 + r) * 40 + hi * 16 + rl] = f2bf(S[mt][2 * sc + hi][r]);
        bf16x8 pa[2], vf[4];
        #pragma unroll
        for (int mt = 0; mt < 2; mt++)
            pa[mt] = *(const bf16x8*)(myP + (mt * 16 + rl) * 40 + quad * 8);
        #pragma unroll
        for (int nd = 0; nd < 4; nd++)
            vf[nd] = *(const bf16x8*)(sKV + (nd * 16 + rl) * 264 + sc * 32 + quad * 8);
        #pragma unroll
        for (int mt = 0; mt < 2; mt++)
            #pragma unroll
            for (int nd = 0; nd < 4; nd++)
                O[mt][nd] = __builtin_amdgcn_mfma_f32_16x16x32_bf16(pa[mt], vf[nd], O[mt][nd], 0, 0, 0);
    }

    // epilogue: normalize by 1/l, write o [T,B,PD] bf16
    #pragma unroll
    for (int mt = 0; mt < 2; mt++)
        #pragma unroll
        for (int nd = 0; nd < 4; nd++)
            #pragma unroll
            for (int r = 0; r < 4; r++) {
                int tg = tbase + mt * 16 + quad * 4 + r;
                int d = nd * 16 + rl;
                o[(size_t)(tg * BS + b) * PD + h * HD + d] = f2bf(O[mt][nd][r] * linv[mt][r]);
            }
}

// ---------------------------------------------------------------------------
extern "C" void kernel_launch(void* const* d_in, const int* in_sizes, int n_in,
                              void* d_out, int out_size, void* d_ws, size_t ws_size,
                              hipStream_t stream) {
    const float* src  = (const float*)d_in[0];
    const float* mask = (const float*)d_in[1];
    const float* Wqkv = (const float*)d_in[2];
    const float* bqkv = (const float*)d_in[3];
    const float* Wo   = (const float*)d_in[4];
    const float* bo   = (const float*)d_in[5];
    const float* ln1g = (const float*)d_in[6];
    const float* ln1b = (const float*)d_in[7];
    const float* ln2g = (const float*)d_in[8];
    const float* ln2b = (const float*)d_in[9];
    const float* W1   = (const float*)d_in[10];
    const float* b1   = (const float*)d_in[11];
    const float* W2   = (const float*)d_in[12];
    const float* b2   = (const float*)d_in[13];
    const float* lnfg = (const float*)d_in[14];
    const float* lnfb = (const float*)d_in[15];

    float* x = (float*)d_out;                                 // fp32 activations
    char* ws = (char*)d_ws;
    unsigned short* qkvT = (unsigned short*)ws;               // 50.3 MB bf16 [3][B][H][T][HD]
    unsigned short* ff   = (unsigned short*)ws;               // aliases qkvT (67.1 MB bf16; disjoint in time)
    unsigned short* h    = (unsigned short*)(ws + 67108864);  // 16.78 MB bf16
    unsigned short* o    = (unsigned short*)(ws + 83886080);  // 16.78 MB bf16
    unsigned short* wbuf = (unsigned short*)(ws + 100663296); // 25.2 MB bf16: all 4 layer weights
    unsigned short* wq = wbuf;
    unsigned short* wo = wbuf + 3145728;
    unsigned short* w1 = wbuf + 4194304;
    unsigned short* w2 = wbuf + 8388608;

    hipMemcpyAsync(x, src, (size_t)ROWS * NF * 4, hipMemcpyDeviceToDevice, stream);

    for (int l = 0; l < NLAYER; l++) {
        const float* wqkv_l = Wqkv + (size_t)l * 3 * PD * NF;
        const float* bqkv_l = bqkv + (size_t)l * 3 * PD;
        const float* wo_l   = Wo + (size_t)l * NF * PD;
        const float* bo_l   = bo + (size_t)l * NF;
        const float* w1_l   = W1 + (size_t)l * FFD * NF;
        const float* b1_l   = b1 + (size_t)l * FFD;
        const float* w2_l   = W2 + (size_t)l * NF * FFD;
        const float* b2_l   = b2 + (size_t)l * NF;

        // convert this layer's 4 weight matrices to bf16 in one launch
        f2bf4_kernel<<<dim3(4096, 4), 256, 0, stream>>>(
            wqkv_l, wo_l, w1_l, w2_l, wq, wo, w1, w2,
            3 * PD * NF, NF * PD, FFD * NF, NF * FFD);
        // h = bf16(LN1(x))
        ln_kernel<1><<<ROWS, 256, 0, stream>>>(x, h, ln1g + (size_t)l * NF, ln1b + (size_t)l * NF);
        // qkvT = (h @ Wqkv^T + bqkv) -> bf16 [3][B][H][T][HD], q scaled
        gemm_mfma<2, 0><<<(ROWS / 128) * (3 * PD / 128), 256, 0, stream>>>(
            h, wq, bqkv_l, nullptr, qkvT, ROWS, 3 * PD, NF);
        // o = attention(qkvT)  (bf16, [T,B,PD])
        attn_mfma<<<BS * NH * 2, 256, 0, stream>>>(qkvT, mask, o);
        // x = x + o @ Wo^T + bo
        gemm_mfma<0, 1><<<(ROWS / 128) * (NF / 128), 256, 0, stream>>>(
            o, wo, bo_l, x, x, ROWS, NF, PD);
        // h = bf16(LN2(x))
        ln_kernel<1><<<ROWS, 256, 0, stream>>>(x, h, ln2g + (size_t)l * NF, ln2b + (size_t)l * NF);
        // ff = bf16(relu(h @ W1^T + b1))
        gemm_mfma<1, 0><<<(ROWS / 128) * (FFD / 128), 256, 0, stream>>>(
            h, w1, b1_l, nullptr, ff, ROWS, FFD, NF);
        // x = x + ff @ W2^T + b2
        gemm_mfma<0, 1><<<(ROWS / 128) * (NF / 128), 256, 0, stream>>>(
            ff, w2, b2_l, x, x, ROWS, NF, FFD);
    }
    // final LN (fp32, in place on d_out)
    ln_kernel<0><<<ROWS, 256, 0, stream>>>(x, x, lnfg, lnfb);
}

// Round 5
// 2171.683 us; speedup vs baseline: 10.1765x; 1.0171x over previous
//
#include <hip/hip_runtime.h>
#include <math.h>

#define TS 256      // seq len
#define BS 32       // batch
#define NF 1024     // features
#define NH 16       // heads
#define HD 64       // head dim
#define PD 1024     // packed dim
#define FFD 4096    // feedforward
#define NLAYER 6
#define ROWS (TS*BS)   // 8192 tokens
#define LNEPS 1e-5f

typedef unsigned int u32;
typedef __attribute__((ext_vector_type(8))) short bf16x8;   // 8 bf16 = 4 VGPRs
typedef __attribute__((ext_vector_type(4))) float f32x4;

__device__ __forceinline__ unsigned short f2bf(float f) {
    u32 u = __builtin_bit_cast(u32, f);
    u32 r = (u + 0x7fffu + ((u >> 16) & 1u)) >> 16;   // RNE
    return (unsigned short)r;
}

// async global->LDS 16B copy (dest must be wave-uniform base + lane*16)
__device__ __forceinline__ void async16(const void* g, void* l) {
    __builtin_amdgcn_global_load_lds(
        (const __attribute__((address_space(1))) u32*)g,
        (__attribute__((address_space(3))) u32*)l, 16, 0, 0);
}

// ---------------------------------------------------------------------------
// LayerNorm: one block (256 threads) per row of N=1024. BF16OUT: emit bf16.
// ---------------------------------------------------------------------------
template <int BF16OUT>
__global__ __launch_bounds__(256)
void ln_kernel(const float* __restrict__ x, void* __restrict__ y,
               const float* __restrict__ g, const float* __restrict__ b) {
    int row = blockIdx.x;
    int tid = threadIdx.x;
    const float4* xr = (const float4*)(x + (size_t)row * NF);
    float4 v = xr[tid];
    float s  = v.x + v.y + v.z + v.w;
    float ss = v.x*v.x + v.y*v.y + v.z*v.z + v.w*v.w;
    #pragma unroll
    for (int off = 32; off > 0; off >>= 1) {
        s  += __shfl_down(s,  off);
        ss += __shfl_down(ss, off);
    }
    __shared__ float ws[4], wss[4];
    int wid = tid >> 6, lane = tid & 63;
    if (lane == 0) { ws[wid] = s; wss[wid] = ss; }
    __syncthreads();
    float sum   = ws[0] + ws[1] + ws[2] + ws[3];
    float sumsq = wss[0] + wss[1] + wss[2] + wss[3];
    float mean = sum * (1.0f / NF);
    float var  = sumsq * (1.0f / NF) - mean * mean;
    float rstd = rsqrtf(var + LNEPS);
    float4 gv = ((const float4*)g)[tid];
    float4 bv = ((const float4*)b)[tid];
    float4 o;
    o.x = (v.x - mean) * rstd * gv.x + bv.x;
    o.y = (v.y - mean) * rstd * gv.y + bv.y;
    o.z = (v.z - mean) * rstd * gv.z + bv.z;
    o.w = (v.w - mean) * rstd * gv.w + bv.w;
    if (BF16OUT) {
        ushort4 ov;
        ov.x = f2bf(o.x); ov.y = f2bf(o.y); ov.z = f2bf(o.z); ov.w = f2bf(o.w);
        ((ushort4*)((unsigned short*)y + (size_t)row * NF))[tid] = ov;
    } else {
        ((float4*)((float*)y + (size_t)row * NF))[tid] = o;
    }
}

// ---------------------------------------------------------------------------
// fp32 -> bf16 convert, 4 arrays in one launch (blockIdx.y selects array)
// ---------------------------------------------------------------------------
__global__ __launch_bounds__(256)
void f2bf4_kernel(const float* __restrict__ s0, const float* __restrict__ s1,
                  const float* __restrict__ s2, const float* __restrict__ s3,
                  unsigned short* __restrict__ d0, unsigned short* __restrict__ d1,
                  unsigned short* __restrict__ d2, unsigned short* __restrict__ d3,
                  int n0, int n1, int n2, int n3) {
    const float* s; unsigned short* d; int n;
    switch (blockIdx.y) {
        case 0: s = s0; d = d0; n = n0; break;
        case 1: s = s1; d = d1; n = n1; break;
        case 2: s = s2; d = d2; n = n2; break;
        default: s = s3; d = d3; n = n3; break;
    }
    int i = (blockIdx.x * 256 + threadIdx.x) * 4;
    if (i >= n) return;
    float4 v = *(const float4*)(s + i);
    ushort4 o;
    o.x = f2bf(v.x); o.y = f2bf(v.y); o.z = f2bf(v.z); o.w = f2bf(v.w);
    *(ushort4*)(d + i) = o;
}

// ---------------------------------------------------------------------------
// bf16 MFMA GEMM (NT): C[M,N] = A[M,K] * B[N,K]^T + bias[N]
// 128x128 tile, BK=64, 256 threads (4 waves, 2x2 quadrants of 64x64).
// DOUBLE-BUFFERED LDS (4 named arrays, 2x-unrolled loop, static buffer
// indices): loads for tile t+1 are issued right after the barrier and
// drained only at the NEXT barrier -> one compute phase of latency overlap.
// LDS rows 64 elems; chunk swizzle: position p holds chunk p ^ (row&7).
// 1D grid, grouped ordering (8 m-blocks per group, n fast).
// MODE: 0 = fp32 row-major out (+optional resid), 1 = bf16 relu out,
//       2 = bf16 out in [3][B][H][T][HD] (QKV transpose, q*0.125)
// ---------------------------------------------------------------------------
template <int MODE, int RESID>
__global__ __launch_bounds__(256)
void gemm_mfma(const unsigned short* __restrict__ A, const unsigned short* __restrict__ B,
               const float* __restrict__ bias, const float* __restrict__ resid,
               void* __restrict__ Cout, int M, int N, int K) {
    __shared__ __align__(16) unsigned short sA0[128 * 64];
    __shared__ __align__(16) unsigned short sA1[128 * 64];
    __shared__ __align__(16) unsigned short sB0[128 * 64];
    __shared__ __align__(16) unsigned short sB1[128 * 64];
    int tid = threadIdx.x;

    // grouped block swizzle: groups of 8 m-blocks x all n-blocks, n fast
    int Nb = N >> 7;
    int bid = blockIdx.x;
    int group = bid / (8 * Nb);
    int rem = bid - group * (8 * Nb);
    int m0 = (group * 8 + rem / Nb) * 128;
    int n0 = (rem % Nb) * 128;

    // staging: 1024 chunks of 8 elems per tile; thread covers idx = tid + 256*it
    int rB = tid >> 3;                       // base row (it=0); row_it = rB + 32*it
    int c0 = (tid & 7) ^ (rB & 7);           // global chunk (same for all it)
    const unsigned short* gA[4];
    const unsigned short* gB[4];
    #pragma unroll
    for (int it = 0; it < 4; it++) {
        gA[it] = A + (size_t)(m0 + rB + 32 * it) * K + c0 * 8;
        gB[it] = B + (size_t)(n0 + rB + 32 * it) * K + c0 * 8;
    }

    int wid = tid >> 6, lane = tid & 63;
    int wm = wid >> 1, wn = wid & 1;
    int quad = lane >> 4, rl = lane & 15;

    int aoff[2][4], boff[2][4];
    #pragma unroll
    for (int ks = 0; ks < 2; ks++)
        #pragma unroll
        for (int t = 0; t < 4; t++) {
            int r = wm * 64 + t * 16 + rl;
            aoff[ks][t] = r * 64 + ((ks * 4 + quad) ^ (r & 7)) * 8;
            int rn = wn * 64 + t * 16 + rl;
            boff[ks][t] = rn * 64 + ((ks * 4 + quad) ^ (rn & 7)) * 8;
        }

    f32x4 acc[4][4] = {};

    auto stage = [&](int t, unsigned short* dA, unsigned short* dB) {
        int kt = t << 6;
        #pragma unroll
        for (int it = 0; it < 4; it++) {
            async16(gA[it] + kt, dA + (tid + 256 * it) * 8);
            async16(gB[it] + kt, dB + (tid + 256 * it) * 8);
        }
    };
    auto compute = [&](const unsigned short* pA, const unsigned short* pB) {
        #pragma unroll
        for (int ks = 0; ks < 2; ks++) {
            bf16x8 a[4], b[4];
            #pragma unroll
            for (int t = 0; t < 4; t++) {
                a[t] = *(const bf16x8*)(pA + aoff[ks][t]);
                b[t] = *(const bf16x8*)(pB + boff[ks][t]);
            }
            #pragma unroll
            for (int i = 0; i < 4; i++)
                #pragma unroll
                for (int j = 0; j < 4; j++)
                    acc[i][j] = __builtin_amdgcn_mfma_f32_16x16x32_bf16(a[i], b[j], acc[i][j], 0, 0, 0);
        }
    };

    int nT = K >> 6;                  // always even (K = 1024 or 4096)
    stage(0, sA0, sB0);
    for (int t = 0; t < nT; t += 2) {
        __syncthreads();              // waves done reading buf1; drains tile-t loads
        stage(t + 1, sA1, sB1);       // prefetch next tile (overlaps compute below)
        compute(sA0, sB0);
        __syncthreads();              // waves done reading buf0; drains tile-(t+1) loads
        if (t + 2 < nT) stage(t + 2, sA0, sB0);
        compute(sA1, sB1);
    }

    // epilogue: C/D layout col=lane&15, row=quad*4+reg
    float bvv[4];
    #pragma unroll
    for (int nt = 0; nt < 4; nt++) bvv[nt] = bias[n0 + wn * 64 + nt * 16 + rl];
    #pragma unroll
    for (int mt = 0; mt < 4; mt++) {
        #pragma unroll
        for (int nt = 0; nt < 4; nt++) {
            #pragma unroll
            for (int r = 0; r < 4; r++) {
                int row = m0 + wm * 64 + mt * 16 + quad * 4 + r;
                int col = n0 + wn * 64 + nt * 16 + rl;
                float v = acc[mt][nt][r] + bvv[nt];
                if (MODE == 0) {
                    if (RESID) v += resid[(size_t)row * N + col];
                    ((float*)Cout)[(size_t)row * N + col] = v;
                } else if (MODE == 1) {
                    v = fmaxf(v, 0.0f);
                    ((unsigned short*)Cout)[(size_t)row * N + col] = f2bf(v);
                } else {
                    int t = row >> 5, bb = row & 31;          // row = t*BS+b
                    int s = col >> 10, hh = (col >> 6) & 15, d = col & 63;
                    if (s == 0) v *= 0.125f;                  // q pre-scale (exact)
                    ((unsigned short*)Cout)[((((size_t)s * BS + bb) * NH + hh) * TS + t) * HD + d] = f2bf(v);
                }
            }
        }
    }
}

// ---------------------------------------------------------------------------
// MFMA attention. qkvT: bf16 [3][B][H][T][HD] (q pre-scaled by 1/8).
// Grid = B*NH*2; block bx: bh = bx>>1, half = bx&1 -> 128 Q-rows.
// 4 waves x 32 rows. K in LDS [256][72]; V^T in LDS [64][264]; per-wave
// P-transpose scratch [32][40]. Output o bf16 [T,B,PD].
// ---------------------------------------------------------------------------
__global__ __launch_bounds__(256, 2)
void attn_mfma(const unsigned short* __restrict__ qkvT, const float* __restrict__ mask,
               unsigned short* __restrict__ o) {
    int bx = blockIdx.x;
    int bh = bx >> 1, half = bx & 1;
    int b = bh >> 4, h = bh & 15;
    const unsigned short* qB = qkvT + (size_t)bh * TS * HD;
    const unsigned short* kB = qB + (size_t)BS * NH * TS * HD;
    const unsigned short* vB = kB + (size_t)BS * NH * TS * HD;
    int tid = threadIdx.x, lane = tid & 63, wid = tid >> 6;
    int quad = lane >> 4, rl = lane & 15;
    int tbase = half * 128 + wid * 32;            // this wave's 32 Q-rows

    __shared__ __align__(16) unsigned short sKV[18432];   // K [256][72] then Vt [64][264]
    __shared__ __align__(16) unsigned short sP[4][1280];  // per-wave P scratch [32][40]

    // stage K [256 s][72]
    #pragma unroll
    for (int it = 0; it < 8; it++) {
        int idx = it * 256 + tid, rrow = idx >> 3, ch = idx & 7;
        *(uint4*)(sKV + rrow * 72 + ch * 8) = *(const uint4*)(kB + (size_t)rrow * 64 + ch * 8);
    }

    // Q fragments (global, already scaled)
    bf16x8 qf[2][2];
    #pragma unroll
    for (int mt = 0; mt < 2; mt++)
        #pragma unroll
        for (int ks = 0; ks < 2; ks++)
            qf[mt][ks] = *(const bf16x8*)(qB + (size_t)(tbase + mt * 16 + rl) * 64 + ks * 32 + quad * 8);

    __syncthreads();

    // scores S[t][s]: A = Q rows, B = K rows
    f32x4 S[2][16] = {};
    #pragma unroll
    for (int nt = 0; nt < 16; nt++) {
        bf16x8 k0 = *(const bf16x8*)(sKV + (nt * 16 + rl) * 72 + quad * 8);
        bf16x8 k1 = *(const bf16x8*)(sKV + (nt * 16 + rl) * 72 + 32 + quad * 8);
        #pragma unroll
        for (int mt = 0; mt < 2; mt++) {
            S[mt][nt] = __builtin_amdgcn_mfma_f32_16x16x32_bf16(qf[mt][0], k0, S[mt][nt], 0, 0, 0);
            S[mt][nt] = __builtin_amdgcn_mfma_f32_16x16x32_bf16(qf[mt][1], k1, S[mt][nt], 0, 0, 0);
        }
    }

    // mask + softmax, rows t = tbase + mt*16 + quad*4 + r, cols s = nt*16 + rl
    float linv[2][4];
    #pragma unroll
    for (int mt = 0; mt < 2; mt++) {
        #pragma unroll
        for (int r = 0; r < 4; r++) {
            int tg = tbase + mt * 16 + quad * 4 + r;
            const float* mrow = mask + (size_t)tg * TS + rl;
            float mx = -3.0e38f;
            #pragma unroll
            for (int nt = 0; nt < 16; nt++) {
                S[mt][nt][r] += mrow[nt * 16];
                mx = fmaxf(mx, S[mt][nt][r]);
            }
            mx = fmaxf(mx, __shfl_xor(mx, 1));
            mx = fmaxf(mx, __shfl_xor(mx, 2));
            mx = fmaxf(mx, __shfl_xor(mx, 4));
            mx = fmaxf(mx, __shfl_xor(mx, 8));
            float sum = 0.0f;
            #pragma unroll
            for (int nt = 0; nt < 16; nt++) {
                float p = __expf(S[mt][nt][r] - mx);
                S[mt][nt][r] = p;
                sum += p;
            }
            sum += __shfl_xor(sum, 1);
            sum += __shfl_xor(sum, 2);
            sum += __shfl_xor(sum, 4);
            sum += __shfl_xor(sum, 8);
            linv[mt][r] = 1.0f / sum;
        }
    }

    __syncthreads();   // all waves done reading K
    // stage V transposed: Vt [64 d][264 s]
    #pragma unroll
    for (int it = 0; it < 8; it++) {
        int idx = it * 256 + tid, srow = idx >> 3, dc = idx & 7;
        bf16x8 vv = *(const bf16x8*)(vB + (size_t)srow * 64 + dc * 8);
        #pragma unroll
        for (int j = 0; j < 8; j++)
            sKV[(dc * 8 + j) * 264 + srow] = (unsigned short)vv[j];
    }
    __syncthreads();

    // PV: O[t][d] = sum_s P[t][s] Vt[d][s]; per-wave P transpose via scratch
    f32x4 O[2][4] = {};
    unsigned short* myP = sP[wid];
    #pragma unroll
    for (int sc = 0; sc < 8; sc++) {
        #pragma unroll
        for (int mt = 0; mt < 2; mt++)
            #pragma unroll
            for (int hi = 0; hi < 2; hi++)
                #pragma unroll
                for (int r = 0; r < 4; r++)
                    myP[(mt * 16 + quad * 4 + r) * 40 + hi * 16 + rl] = f2bf(S[mt][2 * sc + hi][r]);
        bf16x8 pa[2], vf[4];
        #pragma unroll
        for (int mt = 0; mt < 2; mt++)
            pa[mt] = *(const bf16x8*)(myP + (mt * 16 + rl) * 40 + quad * 8);
        #pragma unroll
        for (int nd = 0; nd < 4; nd++)
            vf[nd] = *(const bf16x8*)(sKV + (nd * 16 + rl) * 264 + sc * 32 + quad * 8);
        #pragma unroll
        for (int mt = 0; mt < 2; mt++)
            #pragma unroll
            for (int nd = 0; nd < 4; nd++)
                O[mt][nd] = __builtin_amdgcn_mfma_f32_16x16x32_bf16(pa[mt], vf[nd], O[mt][nd], 0, 0, 0);
    }

    // epilogue: normalize by 1/l, write o [T,B,PD] bf16
    #pragma unroll
    for (int mt = 0; mt < 2; mt++)
        #pragma unroll
        for (int nd = 0; nd < 4; nd++)
            #pragma unroll
            for (int r = 0; r < 4; r++) {
                int tg = tbase + mt * 16 + quad * 4 + r;
                int d = nd * 16 + rl;
                o[(size_t)(tg * BS + b) * PD + h * HD + d] = f2bf(O[mt][nd][r] * linv[mt][r]);
            }
}

// ---------------------------------------------------------------------------
extern "C" void kernel_launch(void* const* d_in, const int* in_sizes, int n_in,
                              void* d_out, int out_size, void* d_ws, size_t ws_size,
                              hipStream_t stream) {
    const float* src  = (const float*)d_in[0];
    const float* mask = (const float*)d_in[1];
    const float* Wqkv = (const float*)d_in[2];
    const float* bqkv = (const float*)d_in[3];
    const float* Wo   = (const float*)d_in[4];
    const float* bo   = (const float*)d_in[5];
    const float* ln1g = (const float*)d_in[6];
    const float* ln1b = (const float*)d_in[7];
    const float* ln2g = (const float*)d_in[8];
    const float* ln2b = (const float*)d_in[9];
    const float* W1   = (const float*)d_in[10];
    const float* b1   = (const float*)d_in[11];
    const float* W2   = (const float*)d_in[12];
    const float* b2   = (const float*)d_in[13];
    const float* lnfg = (const float*)d_in[14];
    const float* lnfb = (const float*)d_in[15];

    float* x = (float*)d_out;                                 // fp32 activations
    char* ws = (char*)d_ws;
    unsigned short* qkvT = (unsigned short*)ws;               // 50.3 MB bf16 [3][B][H][T][HD]
    unsigned short* ff   = (unsigned short*)ws;               // aliases qkvT (67.1 MB bf16; disjoint in time)
    unsigned short* h    = (unsigned short*)(ws + 67108864);  // 16.78 MB bf16
    unsigned short* o    = (unsigned short*)(ws + 83886080);  // 16.78 MB bf16
    unsigned short* wbuf = (unsigned short*)(ws + 100663296); // 25.2 MB bf16: all 4 layer weights
    unsigned short* wq = wbuf;
    unsigned short* wo = wbuf + 3145728;
    unsigned short* w1 = wbuf + 4194304;
    unsigned short* w2 = wbuf + 8388608;

    hipMemcpyAsync(x, src, (size_t)ROWS * NF * 4, hipMemcpyDeviceToDevice, stream);

    for (int l = 0; l < NLAYER; l++) {
        const float* wqkv_l = Wqkv + (size_t)l * 3 * PD * NF;
        const float* bqkv_l = bqkv + (size_t)l * 3 * PD;
        const float* wo_l   = Wo + (size_t)l * NF * PD;
        const float* bo_l   = bo + (size_t)l * NF;
        const float* w1_l   = W1 + (size_t)l * FFD * NF;
        const float* b1_l   = b1 + (size_t)l * FFD;
        const float* w2_l   = W2 + (size_t)l * NF * FFD;
        const float* b2_l   = b2 + (size_t)l * NF;

        // convert this layer's 4 weight matrices to bf16 in one launch
        f2bf4_kernel<<<dim3(4096, 4), 256, 0, stream>>>(
            wqkv_l, wo_l, w1_l, w2_l, wq, wo, w1, w2,
            3 * PD * NF, NF * PD, FFD * NF, NF * FFD);
        // h = bf16(LN1(x))
        ln_kernel<1><<<ROWS, 256, 0, stream>>>(x, h, ln1g + (size_t)l * NF, ln1b + (size_t)l * NF);
        // qkvT = (h @ Wqkv^T + bqkv) -> bf16 [3][B][H][T][HD], q scaled
        gemm_mfma<2, 0><<<(ROWS / 128) * (3 * PD / 128), 256, 0, stream>>>(
            h, wq, bqkv_l, nullptr, qkvT, ROWS, 3 * PD, NF);
        // o = attention(qkvT)  (bf16, [T,B,PD])
        attn_mfma<<<BS * NH * 2, 256, 0, stream>>>(qkvT, mask, o);
        // x = x + o @ Wo^T + bo
        gemm_mfma<0, 1><<<(ROWS / 128) * (NF / 128), 256, 0, stream>>>(
            o, wo, bo_l, x, x, ROWS, NF, PD);
        // h = bf16(LN2(x))
        ln_kernel<1><<<ROWS, 256, 0, stream>>>(x, h, ln2g + (size_t)l * NF, ln2b + (size_t)l * NF);
        // ff = bf16(relu(h @ W1^T + b1))
        gemm_mfma<1, 0><<<(ROWS / 128) * (FFD / 128), 256, 0, stream>>>(
            h, w1, b1_l, nullptr, ff, ROWS, FFD, NF);
        // x = x + ff @ W2^T + b2
        gemm_mfma<0, 1><<<(ROWS / 128) * (NF / 128), 256, 0, stream>>>(
            ff, w2, b2_l, x, x, ROWS, NF, FFD);
    }
    // final LN (fp32, in place on d_out)
    ln_kernel<0><<<ROWS, 256, 0, stream>>>(x, x, lnfg, lnfb);
}